// Round 1
// baseline (1378.711 us; speedup 1.0000x reference)
//
#include <hip/hip_runtime.h>
#include <cstdint>

// Problem constants
#define B_   8
#define ROI_ 90
#define T_   200
#define H_   3
#define F_   64
#define DH_  64
#define R_   270
#define NBN  144000.0f   // B*ROI*T samples per BN channel

__device__ __forceinline__ float elu_f(float x) { return x > 0.f ? x : expm1f(x); }
__device__ __forceinline__ float sigm_f(float x) { return 1.f / (1.f + __expf(-x)); }
__device__ __forceinline__ float tanh_f(float x) {
    float xc = fminf(fmaxf(x, -30.f), 30.f);
    float e = __expf(-2.f * xc);
    return (1.f - e) / (1.f + e);
}
__device__ __forceinline__ void fma4(float4& acc, float s, const float4 v) {
    acc.x = fmaf(s, v.x, acc.x); acc.y = fmaf(s, v.y, acc.y);
    acc.z = fmaf(s, v.z, acc.z); acc.w = fmaf(s, v.w, acc.w);
}
__device__ __forceinline__ float dot4(const float4 a, const float4 b) {
    return fmaf(a.x, b.x, fmaf(a.y, b.y, fmaf(a.z, b.z, a.w * b.w)));
}

// ---------------------------------------------------------------------------
// K1: per-(b,t,h): v = mask@x + eps*x ; z1pre = v@W1 + b1 ; BN1 stat partials
// grid 4800 (b*t*h), block 256
// LDS: W1 [64][64] (16KB) | xs/v [96][68] (26112B) | mask bf16 [96][90] (17280B, red aliases)
// ---------------------------------------------------------------------------
__global__ __launch_bounds__(256) void k_layer1(
    const float* __restrict__ x, const float* __restrict__ a,
    const float* __restrict__ eps_param, const float* __restrict__ W1,
    const float* __restrict__ b1, float* __restrict__ zbuf,
    float* __restrict__ sum1, float* __restrict__ sq1)
{
    __shared__ __align__(16) char smem[16384 + 26112 + 17280];
    float* wlds = (float*)smem;                                   // [f][g] stride 64
    float* xsv  = (float*)(smem + 16384);                         // [96][68]
    unsigned short* msk = (unsigned short*)(smem + 16384 + 26112);// [96][90] bf16 0/1
    float* red = (float*)msk;                                     // reused after matmul

    int bid = blockIdx.x;
    int h = bid % 3;
    int t = (bid / 3) % 200;
    int b = bid / 600;
    int tid = threadIdx.x;

    // stage W1[h] ([f][g], packed)
    {
        const float4* wsrc = (const float4*)(W1 + h * 4096);
        for (int idx = tid; idx < 1024; idx += 256)
            *(float4*)&wlds[idx * 4] = wsrc[idx];
    }
    // stage x rows for this (b,t,h): xs[j][f]
    {
        size_t xb = ((((size_t)b * 90) * 200 + t) * 3 + h) * 64;
        for (int idx = tid; idx < 1440; idx += 256) {
            int j = idx >> 4, fq = idx & 15;
            float4 v = *(const float4*)(x + xb + (size_t)j * 38400 + fq * 4);
            *(float4*)&xsv[j * 68 + fq * 4] = v;
        }
    }
    // stage binary mask as bf16 bits (rows 90..95 zeroed)
    {
        size_t ab = ((((size_t)b * 90) * 200 + t) * 3 + h) * 90;
        for (int idx = tid; idx < 8640; idx += 256) {
            int i = idx / 90, j = idx - i * 90;
            unsigned short mv = 0;
            if (i < 90) {
                float av = a[ab + (size_t)i * 54000 + j];
                mv = (av != 0.f) ? (unsigned short)0x3F80 : (unsigned short)0;
            }
            msk[idx] = mv;
        }
    }
    __syncthreads();

    // agg: each thread: 4 f's (f0..f0+3), 6 strided i's
    int fg = tid & 15, ig = tid >> 4;
    int f0 = fg * 4;
    float4 acc[6];
#pragma unroll
    for (int k = 0; k < 6; k++) acc[k] = make_float4(0.f, 0.f, 0.f, 0.f);
    for (int j = 0; j < 90; j++) {
        float4 xv = *(float4*)&xsv[j * 68 + f0];
#pragma unroll
        for (int k = 0; k < 6; k++) {
            unsigned int mb = msk[(ig + 16 * k) * 90 + j];
            float m = __uint_as_float(mb << 16);
            fma4(acc[k], m, xv);
        }
    }
    float ep = eps_param[h];
#pragma unroll
    for (int k = 0; k < 6; k++) {
        int i = ig + 16 * k;
        if (i < 90) {
            float4 xv = *(float4*)&xsv[i * 68 + f0];
            fma4(acc[k], ep, xv);
        }
    }
    __syncthreads();             // all xs reads done -> safe to overwrite with v
#pragma unroll
    for (int k = 0; k < 6; k++) {
        int i = ig + 16 * k;
        if (i < 90) *(float4*)&xsv[i * 68 + f0] = acc[k];
    }
    __syncthreads();

    // z1 = v @ W1 + b1 : thread = 4 g's x 6 strided i's
    int gg = tid & 15, im = tid >> 4;
    int g0 = gg * 4;
    float4 bv = *(const float4*)(b1 + h * 64 + g0);
    float4 z[6];
#pragma unroll
    for (int k = 0; k < 6; k++) z[k] = bv;
    for (int fq = 0; fq < 16; fq++) {
        float4 wv0 = *(float4*)&wlds[(fq * 4 + 0) * 64 + g0];
        float4 wv1 = *(float4*)&wlds[(fq * 4 + 1) * 64 + g0];
        float4 wv2 = *(float4*)&wlds[(fq * 4 + 2) * 64 + g0];
        float4 wv3 = *(float4*)&wlds[(fq * 4 + 3) * 64 + g0];
#pragma unroll
        for (int k = 0; k < 6; k++) {
            float4 vv = *(float4*)&xsv[(im + 16 * k) * 68 + fq * 4];
            fma4(z[k], vv.x, wv0); fma4(z[k], vv.y, wv1);
            fma4(z[k], vv.z, wv2); fma4(z[k], vv.w, wv3);
        }
    }
    // write + BN1 partial sums
    float4 s = make_float4(0, 0, 0, 0), s2 = make_float4(0, 0, 0, 0);
    size_t zb = ((((size_t)b * 90) * 200 + t) * 3 + h) * 64;
#pragma unroll
    for (int k = 0; k < 6; k++) {
        int i = im + 16 * k;
        if (i < 90) {
            *(float4*)(zbuf + zb + (size_t)i * 38400 + g0) = z[k];
            s.x += z[k].x; s.y += z[k].y; s.z += z[k].z; s.w += z[k].w;
            s2.x += z[k].x * z[k].x; s2.y += z[k].y * z[k].y;
            s2.z += z[k].z * z[k].z; s2.w += z[k].w * z[k].w;
        }
    }
    *(float4*)&red[im * 64 + g0] = s;
    *(float4*)&red[1024 + im * 64 + g0] = s2;
    __syncthreads();
    if (tid < 64) {
        float S = 0.f, S2 = 0.f;
        for (int q = 0; q < 16; q++) { S += red[q * 64 + tid]; S2 += red[1024 + q * 64 + tid]; }
        atomicAdd(&sum1[h * 64 + tid], S);
        atomicAdd(&sq1[h * 64 + tid], S2);
    }
}

// ---------------------------------------------------------------------------
// K2: finalize BN stats -> fused scale/shift
// ---------------------------------------------------------------------------
__global__ void k_bnfin(const float* __restrict__ sum, const float* __restrict__ sq,
                        const float* __restrict__ g, const float* __restrict__ be,
                        float* __restrict__ scale, float* __restrict__ shift)
{
    int c = threadIdx.x;
    if (c < 192) {
        float mean = sum[c] / NBN;
        float var = fmaxf(sq[c] / NBN - mean * mean, 0.f);
        float inv = rsqrtf(var + 1e-5f);
        float sc = g[c] * inv;
        scale[c] = sc;
        shift[c] = fmaf(-mean, sc, be[c]);
    }
}

// ---------------------------------------------------------------------------
// K3: z = elu(bn1(z1pre)); z2pre = z@W2 + b2 (in-place in zbuf); BN2 partials
// ---------------------------------------------------------------------------
__global__ __launch_bounds__(256) void k_layer2(
    float* zbuf, const float* __restrict__ W2, const float* __restrict__ b2,
    const float* __restrict__ scale1, const float* __restrict__ shift1,
    float* __restrict__ sum2, float* __restrict__ sq2)
{
    __shared__ __align__(16) float wlds[4096];
    __shared__ __align__(16) float zt[96 * 68];
    __shared__ float red[2048];

    int bid = blockIdx.x;
    int h = bid % 3;
    int t = (bid / 3) % 200;
    int b = bid / 600;
    int tid = threadIdx.x;

    {
        const float4* wsrc = (const float4*)(W2 + h * 4096);
        for (int idx = tid; idx < 1024; idx += 256)
            *(float4*)&wlds[idx * 4] = wsrc[idx];
    }
    size_t zb = ((((size_t)b * 90) * 200 + t) * 3 + h) * 64;
    for (int idx = tid; idx < 1440; idx += 256) {
        int j = idx >> 4, fq = idx & 15;
        float4 v = *(const float4*)(zbuf + zb + (size_t)j * 38400 + fq * 4);
        float4 sc = *(const float4*)(scale1 + h * 64 + fq * 4);
        float4 sh = *(const float4*)(shift1 + h * 64 + fq * 4);
        v.x = elu_f(fmaf(v.x, sc.x, sh.x));
        v.y = elu_f(fmaf(v.y, sc.y, sh.y));
        v.z = elu_f(fmaf(v.z, sc.z, sh.z));
        v.w = elu_f(fmaf(v.w, sc.w, sh.w));
        *(float4*)&zt[j * 68 + fq * 4] = v;
    }
    __syncthreads();

    int gg = tid & 15, im = tid >> 4;
    int g0 = gg * 4;
    float4 bv = *(const float4*)(b2 + h * 64 + g0);
    float4 z[6];
#pragma unroll
    for (int k = 0; k < 6; k++) z[k] = bv;
    for (int fq = 0; fq < 16; fq++) {
        float4 wv0 = *(float4*)&wlds[(fq * 4 + 0) * 64 + g0];
        float4 wv1 = *(float4*)&wlds[(fq * 4 + 1) * 64 + g0];
        float4 wv2 = *(float4*)&wlds[(fq * 4 + 2) * 64 + g0];
        float4 wv3 = *(float4*)&wlds[(fq * 4 + 3) * 64 + g0];
#pragma unroll
        for (int k = 0; k < 6; k++) {
            float4 vv = *(float4*)&zt[(im + 16 * k) * 68 + fq * 4];
            fma4(z[k], vv.x, wv0); fma4(z[k], vv.y, wv1);
            fma4(z[k], vv.z, wv2); fma4(z[k], vv.w, wv3);
        }
    }
    float4 s = make_float4(0, 0, 0, 0), s2 = make_float4(0, 0, 0, 0);
#pragma unroll
    for (int k = 0; k < 6; k++) {
        int i = im + 16 * k;
        if (i < 90) {
            *(float4*)(zbuf + zb + (size_t)i * 38400 + g0) = z[k];
            s.x += z[k].x; s.y += z[k].y; s.z += z[k].z; s.w += z[k].w;
            s2.x += z[k].x * z[k].x; s2.y += z[k].y * z[k].y;
            s2.z += z[k].z * z[k].z; s2.w += z[k].w * z[k].w;
        }
    }
    *(float4*)&red[im * 64 + g0] = s;
    *(float4*)&red[1024 + im * 64 + g0] = s2;
    __syncthreads();
    if (tid < 64) {
        float S = 0.f, S2 = 0.f;
        for (int q = 0; q < 16; q++) { S += red[q * 64 + tid]; S2 += red[1024 + q * 64 + tid]; }
        atomicAdd(&sum2[h * 64 + tid], S);
        atomicAdd(&sq2[h * 64 + tid], S2);
    }
}

// ---------------------------------------------------------------------------
// K5: z = max(bn2(z2pre), 0) [since relu(elu(x)) == max(x,0)];
//     gi[t][r][b][g] = z_row . Wih[r][g][:] + bih[r][g]
// grid 1080 (r x t-quarter), block 256
// ---------------------------------------------------------------------------
__global__ __launch_bounds__(256) void k_giproj(
    const float* __restrict__ zin, const float* __restrict__ Wih,
    const float* __restrict__ bih, const float* __restrict__ scale2,
    const float* __restrict__ shift2, float* __restrict__ gi)
{
    __shared__ __align__(16) float wl[192 * 68];   // 52224B
    __shared__ __align__(16) float zl[40 * 68];    // 10880B
    __shared__ float bsc[64], bsh[64];

    int bid = blockIdx.x;
    int r = bid >> 2, tq = bid & 3;
    int roi = r / 3, h = r - roi * 3;
    int tid = threadIdx.x;

    if (tid < 64) { bsc[tid] = scale2[h * 64 + tid]; bsh[tid] = shift2[h * 64 + tid]; }
    {
        const float4* wsrc = (const float4*)(Wih + (size_t)r * 12288);
        for (int idx = tid; idx < 3072; idx += 256) {
            int g = idx >> 4, fq = idx & 15;
            *(float4*)&wl[g * 68 + fq * 4] = wsrc[idx];
        }
    }
    int gg = tid & 31, rg = tid >> 5;
    float bihv[6];
#pragma unroll
    for (int k = 0; k < 6; k++) bihv[k] = bih[r * 192 + gg + 32 * k];

    for (int ci = 0; ci < 10; ci++) {
        int t0 = tq * 50 + ci * 5;
        __syncthreads();   // protects zl (prev iter) and initial wl staging
        for (int idx = tid; idx < 640; idx += 256) {
            int row = idx >> 4, fq = idx & 15;
            int dt = row >> 3, bb = row & 7;
            size_t addr = ((((size_t)bb * 90 + roi) * 200 + (t0 + dt)) * 3 + h) * 64 + fq * 4;
            float4 v = *(const float4*)(zin + addr);
            float4 sc = *(const float4*)&bsc[fq * 4];
            float4 sh = *(const float4*)&bsh[fq * 4];
            v.x = fmaxf(fmaf(v.x, sc.x, sh.x), 0.f);
            v.y = fmaxf(fmaf(v.y, sc.y, sh.y), 0.f);
            v.z = fmaxf(fmaf(v.z, sc.z, sh.z), 0.f);
            v.w = fmaxf(fmaf(v.w, sc.w, sh.w), 0.f);
            *(float4*)&zl[row * 68 + fq * 4] = v;
        }
        __syncthreads();
        float acc[6][5];
#pragma unroll
        for (int k = 0; k < 6; k++)
#pragma unroll
            for (int rr = 0; rr < 5; rr++) acc[k][rr] = 0.f;
        for (int fq = 0; fq < 16; fq++) {
            float4 wv[6];
#pragma unroll
            for (int k = 0; k < 6; k++) wv[k] = *(float4*)&wl[(gg + 32 * k) * 68 + fq * 4];
#pragma unroll
            for (int rr = 0; rr < 5; rr++) {
                float4 zv = *(float4*)&zl[(rg * 5 + rr) * 68 + fq * 4];
#pragma unroll
                for (int k = 0; k < 6; k++) {
                    acc[k][rr] = fmaf(zv.x, wv[k].x, acc[k][rr]);
                    acc[k][rr] = fmaf(zv.y, wv[k].y, acc[k][rr]);
                    acc[k][rr] = fmaf(zv.z, wv[k].z, acc[k][rr]);
                    acc[k][rr] = fmaf(zv.w, wv[k].w, acc[k][rr]);
                }
            }
        }
#pragma unroll
        for (int rr = 0; rr < 5; rr++) {
            int row = rg * 5 + rr; int dt = row >> 3, bb = row & 7;
            size_t gb = (((size_t)(t0 + dt) * 270 + r) * 8 + bb) * 192 + gg;
#pragma unroll
            for (int k = 0; k < 6; k++) gi[gb + 32 * k] = acc[k][rr] + bihv[k];
        }
    }
}

// ---------------------------------------------------------------------------
// K6: GRU scan. grid 1080 (r x b-pair), block 256.
// Whh kept in registers (48/thread), d-split 4, LDS reduction, 2 barriers/step
// ---------------------------------------------------------------------------
__global__ __launch_bounds__(256) void k_gru(
    const float* __restrict__ gi, const float* __restrict__ Whh,
    const float* __restrict__ bhh, float* __restrict__ out)
{
    __shared__ __align__(16) float staged[64 * 68]; // 17408B, Whh staging
    __shared__ __align__(16) float red[1536];       // [dg][gt][m][lb]
    __shared__ float hl[2 * 68];

    int bid = blockIdx.x;
    int r = bid >> 2, bq = bid & 3;
    int roi = r / 3, h = r - roi * 3;
    int b0 = bq * 2;
    int tid = threadIdx.x;
    int gt = tid & 63, dg = tid >> 6;

    // Whh -> registers via coalesced LDS staging (3 chunks of 64 g)
    float4 wreg[3][4];
    const float4* wsrc = (const float4*)(Whh + (size_t)r * 12288);
    for (int c = 0; c < 3; c++) {
        __syncthreads();
        for (int idx = tid; idx < 1024; idx += 256) {
            int gl = idx >> 4, fq = idx & 15;
            *(float4*)&staged[gl * 68 + fq * 4] = wsrc[c * 1024 + idx];
        }
        __syncthreads();
#pragma unroll
        for (int dq = 0; dq < 4; dq++)
            wreg[c][dq] = *(float4*)&staged[gt * 68 + dg * 16 + dq * 4];
    }

    int lb = tid & 1, d = tid >> 1;
    float bh0 = 0.f, bh1 = 0.f, bh2 = 0.f;
    const float* gib = gi + ((size_t)r * 8 + b0 + lb) * 192;
    size_t ob = 0;
    if (tid < 128) {
        bh0 = bhh[r * 192 + d];
        bh1 = bhh[r * 192 + 64 + d];
        bh2 = bhh[r * 192 + 128 + d];
        ob = ((((size_t)(b0 + lb) * 90 + roi) * 200) * 3 + h) * 64 + d;
    }
    if (tid < 136) hl[tid] = 0.f;
    __syncthreads();

    const size_t gstep = 270ull * 8 * 192;
    for (int t = 0; t < 200; t++) {
        // partial gh for g = gt + 64*m over d-range [dg*16, dg*16+16)
        float a00 = 0.f, a01 = 0.f, a02 = 0.f, a10 = 0.f, a11 = 0.f, a12 = 0.f;
#pragma unroll
        for (int dq = 0; dq < 4; dq++) {
            float4 h0 = *(float4*)&hl[dg * 16 + dq * 4];
            float4 h1 = *(float4*)&hl[68 + dg * 16 + dq * 4];
            float4 w0 = wreg[0][dq], w1 = wreg[1][dq], w2 = wreg[2][dq];
            a00 += dot4(w0, h0); a01 += dot4(w1, h0); a02 += dot4(w2, h0);
            a10 += dot4(w0, h1); a11 += dot4(w1, h1); a12 += dot4(w2, h1);
        }
        int rb = (dg * 64 + gt) * 6;
        *(float2*)&red[rb + 0] = make_float2(a00, a10);
        *(float2*)&red[rb + 2] = make_float2(a01, a11);
        *(float2*)&red[rb + 4] = make_float2(a02, a12);
        __syncthreads();
        if (tid < 128) {
            int base = d * 6 + lb;
            float ghr = red[base]     + red[384 + base]     + red[768 + base]     + red[1152 + base]     + bh0;
            float ghz = red[base + 2] + red[384 + base + 2] + red[768 + base + 2] + red[1152 + base + 2] + bh1;
            float ghn = red[base + 4] + red[384 + base + 4] + red[768 + base + 4] + red[1152 + base + 4] + bh2;
            const float* gp = gib + (size_t)t * gstep;
            float rr_ = sigm_f(gp[d] + ghr);
            float uu  = sigm_f(gp[64 + d] + ghz);
            float nn  = tanh_f(fmaf(rr_, ghn, gp[128 + d]));
            float hold = hl[lb * 68 + d];
            float hnew = fmaf(uu, hold - nn, nn);   // (1-u)*n + u*h
            hl[lb * 68 + d] = hnew;
            out[ob + (size_t)t * 192] = hnew;
        }
        __syncthreads();
    }
}

// ---------------------------------------------------------------------------
extern "C" void kernel_launch(void* const* d_in, const int* in_sizes, int n_in,
                              void* d_out, int out_size, void* d_ws, size_t ws_size,
                              hipStream_t stream)
{
    const float* x   = (const float*)d_in[0];
    const float* a   = (const float*)d_in[1];
    const float* eps = (const float*)d_in[2];
    const float* W1  = (const float*)d_in[3];
    const float* b1  = (const float*)d_in[4];
    const float* g1  = (const float*)d_in[5];
    const float* be1 = (const float*)d_in[6];
    const float* W2  = (const float*)d_in[7];
    const float* b2  = (const float*)d_in[8];
    const float* g2  = (const float*)d_in[9];
    const float* be2 = (const float*)d_in[10];
    const float* Wih = (const float*)d_in[11];
    const float* Whh = (const float*)d_in[12];
    const float* bih = (const float*)d_in[13];
    const float* bhh = (const float*)d_in[14];
    float* out = (float*)d_out;

    float* wsf = (float*)d_ws;
    float* sum1 = wsf,        *sq1 = wsf + 192;
    float* sum2 = wsf + 384,  *sq2 = wsf + 576;
    float* scale1 = wsf + 768,  *shift1 = wsf + 960;
    float* scale2 = wsf + 1152, *shift2 = wsf + 1344;
    float* zbuf = wsf + 2048;                 // 27,648,000 floats
    float* gi   = zbuf + 27648000ull;         // 82,944,000 floats

    hipMemsetAsync(wsf, 0, 768 * sizeof(float), stream);
    hipLaunchKernelGGL(k_layer1, dim3(4800), dim3(256), 0, stream,
                       x, a, eps, W1, b1, zbuf, sum1, sq1);
    hipLaunchKernelGGL(k_bnfin, dim3(1), dim3(256), 0, stream,
                       sum1, sq1, g1, be1, scale1, shift1);
    hipLaunchKernelGGL(k_layer2, dim3(4800), dim3(256), 0, stream,
                       zbuf, W2, b2, scale1, shift1, sum2, sq2);
    hipLaunchKernelGGL(k_bnfin, dim3(1), dim3(256), 0, stream,
                       sum2, sq2, g2, be2, scale2, shift2);
    hipLaunchKernelGGL(k_giproj, dim3(1080), dim3(256), 0, stream,
                       zbuf, Wih, bih, scale2, shift2, gi);
    hipLaunchKernelGGL(k_gru, dim3(1080), dim3(256), 0, stream,
                       gi, Whh, bhh, out);
}